// Round 1
// baseline (244.308 us; speedup 1.0000x reference)
//
#include <hip/hip_runtime.h>
#include <hip/hip_fp16.h>
#include <hip/hip_bf16.h>

// Problem constants (B=4, C=128, H=W=64 -> HW=4096)
#define BATCH 4
#define CCH   128
#define HWSZ  4096

typedef _Float16 half8 __attribute__((ext_vector_type(8)));
typedef short short8 __attribute__((ext_vector_type(8)));
typedef float floatx4 __attribute__((ext_vector_type(4)));
typedef unsigned short ushort4v __attribute__((ext_vector_type(4)));

__device__ __forceinline__ unsigned short f2bf(float f) {
    union { float f; unsigned u; } v; v.f = f;
    unsigned r = (v.u + 0x7fffu + ((v.u >> 16) & 1u)) >> 16;
    return (unsigned short)r;
}

// prep: x fp32 [B][C][HW] -> xt fp16 [B][HW][C] (transposed), xf bf16 [B][C][HW]
__global__ __launch_bounds__(256) void prep_kernel(
    const float* __restrict__ x1, const float* __restrict__ x2,
    _Float16* __restrict__ x1t, _Float16* __restrict__ x2t,
    unsigned short* __restrict__ x1f, unsigned short* __restrict__ x2f)
{
    __shared__ float lds[32][33];
    int idx = blockIdx.x;            // 0..4095
    int which = idx >> 11;           // 0: x1, 1: x2
    int r = idx & 2047;
    int cb  = r & 3;                 // C/32  = 4
    int hwb = (r >> 2) & 127;        // HW/32 = 128
    int b   = r >> 9;                // 4 batches
    const float* x = which ? x2 : x1;
    _Float16* xt = which ? x2t : x1t;
    unsigned short* xf = which ? x2f : x1f;
    int tid = threadIdx.x;
    int tc = tid >> 5, th = tid & 31;
    #pragma unroll
    for (int k = 0; k < 4; ++k) {
        int cl = tc + 8 * k;
        int c = cb * 32 + cl, hw = hwb * 32 + th;
        float v = x[((size_t)b * CCH + c) * HWSZ + hw];
        lds[cl][th] = v;
        xf[((size_t)b * CCH + c) * HWSZ + hw] = f2bf(v);
    }
    __syncthreads();
    #pragma unroll
    for (int k = 0; k < 4; ++k) {
        int hl = tc + 8 * k;
        xt[((size_t)b * HWSZ + hwb * 32 + hl) * CCH + cb * 32 + th] =
            (_Float16)lds[th][hl];
    }
}

// Fused pass. Computes, for its 64-wide slice `blk` of the block-dim:
//   D_A[row=loopdim, col=blockdim] = sum_c loopT[row][c]*blockT[col][c]   (fp16 MFMA, K=128)
//   E = exp(D_A)  (bf16, into LDS [col][row] layout, stride-72 padded)
//   accP[c][col] += sum_row loopF[c][row] * E[row][col]                   (bf16 MFMA)
//   colsum[col]  += sum_row E
// Epilogue: att = accP/colsum; out[blockdim] (+)= cw * sum_c gw[c]*sigmoid(att)*xe[c][blockdim]
// pass2 (out2 over m): loopT=x1t, blockT=x2t, loopF=x1f, xe=x2, ACCUM=0
// pass3 (out1 over n): loopT=x2t, blockT=x1t, loopF=x2f, xe=x1, ACCUM=1
template<int ACCUM>
__global__ __launch_bounds__(512, 2) void fused_pass(
    const _Float16* __restrict__ loopT,
    const _Float16* __restrict__ blockT,
    const unsigned short* __restrict__ loopF,
    const float* __restrict__ xe,
    const float* __restrict__ gw,
    const float* __restrict__ cwp,
    float* __restrict__ out)
{
    __shared__ unsigned short ldsE[64][72];   // [block-dim col][loop-dim row], pad 72 -> <=2-way banks
    __shared__ float colsum[64];
    __shared__ float outp[64];
    __shared__ float gws[CCH];

    int bid = blockIdx.x;
    int xcd = bid & 7, grp = bid >> 3;
    int b   = xcd >> 1;                 // 2 XCDs per batch -> ~2MB L2 working set each
    int blk = grp * 2 + (xcd & 1);      // 0..63
    int tid = threadIdx.x;
    int wave = tid >> 6, lane = tid & 63;
    int l16 = lane & 15, lg = lane >> 4;
    int nt = wave & 3, mh = wave >> 2;

    if (tid < 64) { colsum[tid] = 0.f; outp[tid] = 0.f; }
    if (tid < CCH) gws[tid] = gw[tid];

    const _Float16* lT = loopT + (size_t)b * HWSZ * CCH;
    const _Float16* bT = blockT + (size_t)b * HWSZ * CCH;
    const unsigned short* lF = loopF + (size_t)b * CCH * HWSZ;

    // hoist B-operand (block-dim side) fragments: rows blk*64+mh*32+t*16+l16, k=c
    half8 bfrag[2][4];
    #pragma unroll
    for (int t = 0; t < 2; ++t)
        #pragma unroll
        for (int ks = 0; ks < 4; ++ks)
            bfrag[t][ks] = *(const half8*)&bT[
                ((size_t)(blk * 64 + mh * 32 + t * 16 + l16)) * CCH + ks * 32 + lg * 8];

    float csum0 = 0.f, csum1 = 0.f;
    floatx4 accP[4];
    #pragma unroll
    for (int mt = 0; mt < 4; ++mt) accP[mt] = (floatx4){0.f, 0.f, 0.f, 0.f};

    const _Float16* aBase = lT + (size_t)(nt * 16 + l16) * CCH + lg * 8;
    const unsigned short* fBase = lF + (size_t)(wave * 16 + l16) * HWSZ + lg * 8;

    for (int ch = 0; ch < 64; ++ch) {
        // ---- Gram GEMM: A-chunk [64 loop rows x 64 block cols], K = C = 128 (fp16)
        const _Float16* ap = aBase + (size_t)ch * 64 * CCH;
        half8 af[4];
        #pragma unroll
        for (int ks = 0; ks < 4; ++ks) af[ks] = *(const half8*)(ap + ks * 32);
        floatx4 accA0 = {0.f, 0.f, 0.f, 0.f}, accA1 = {0.f, 0.f, 0.f, 0.f};
        #pragma unroll
        for (int ks = 0; ks < 4; ++ks) {
            accA0 = __builtin_amdgcn_mfma_f32_16x16x32_f16(af[ks], bfrag[0][ks], accA0, 0, 0, 0);
            accA1 = __builtin_amdgcn_mfma_f32_16x16x32_f16(af[ks], bfrag[1][ks], accA1, 0, 0, 0);
        }
        // ---- exp (no max subtraction: |A| < 88 with overwhelming probability) + bf16 pack
        ushort4v e0, e1;
        #pragma unroll
        for (int rr = 0; rr < 4; ++rr) {
            float v0 = __expf(accA0[rr]); csum0 += v0; e0[rr] = f2bf(v0);
            float v1 = __expf(accA1[rr]); csum1 += v1; e1[rr] = f2bf(v1);
        }
        __syncthreads();   // previous chunk's PV reads complete
        // D-frag: lane holds rows nt*16+4*lg+rr (consecutive) at col mh*32+t*16+l16
        *(ushort4v*)&ldsE[mh * 32 + 0 * 16 + l16][nt * 16 + lg * 4] = e0;
        *(ushort4v*)&ldsE[mh * 32 + 1 * 16 + l16][nt * 16 + lg * 4] = e1;
        __syncthreads();   // E tile visible
        // ---- PV: accP[c-tile=wave][all 4 block-col tiles] over k = 64 loop rows (bf16)
        const unsigned short* fp = fBase + ch * 64;
        short8 pa0 = *(const short8*)(fp);
        short8 pa1 = *(const short8*)(fp + 32);
        #pragma unroll
        for (int mt = 0; mt < 4; ++mt) {
            short8 pb0 = *(const short8*)&ldsE[mt * 16 + l16][0 * 32 + lg * 8];
            short8 pb1 = *(const short8*)&ldsE[mt * 16 + l16][1 * 32 + lg * 8];
            accP[mt] = __builtin_amdgcn_mfma_f32_16x16x32_bf16(pa0, pb0, accP[mt], 0, 0, 0);
            accP[mt] = __builtin_amdgcn_mfma_f32_16x16x32_bf16(pa1, pb1, accP[mt], 0, 0, 0);
        }
    }

    // ---- colsum reduction: lanes l, l+16, l+32, l+48 share a column
    {
        float v = csum0;
        v += __shfl_xor(v, 16, 64); v += __shfl_xor(v, 32, 64);
        if (lane < 16) atomicAdd(&colsum[mh * 32 + 0 * 16 + lane], v);
        float w = csum1;
        w += __shfl_xor(w, 16, 64); w += __shfl_xor(w, 32, 64);
        if (lane < 16) atomicAdd(&colsum[mh * 32 + 1 * 16 + lane], w);
    }
    __syncthreads();

    // ---- epilogue: normalize, sigmoid, gate, contract over C
    float cw = cwp[0];
    int c0 = wave * 16;
    #pragma unroll
    for (int mt = 0; mt < 4; ++mt) {
        int ml = mt * 16 + l16;
        float inv = 1.f / colsum[ml];
        float p = 0.f;
        #pragma unroll
        for (int rr = 0; rr < 4; ++rr) {
            int c = c0 + lg * 4 + rr;
            float att = accP[mt][rr] * inv;
            float mask = 1.f / (1.f + __expf(-att));
            float xv = xe[((size_t)b * CCH + c) * HWSZ + blk * 64 + ml];
            p += gws[c] * mask * xv;
        }
        p += __shfl_xor(p, 16, 64); p += __shfl_xor(p, 32, 64);
        if (lane < 16) atomicAdd(&outp[mt * 16 + lane], p);
    }
    __syncthreads();
    if (tid < 64) {
        float v = cw * outp[tid];
        size_t o = (size_t)b * HWSZ + blk * 64 + tid;
        if (ACCUM) out[o] += v; else out[o] = v;
    }
}

extern "C" void kernel_launch(void* const* d_in, const int* in_sizes, int n_in,
                              void* d_out, int out_size, void* d_ws, size_t ws_size,
                              hipStream_t stream) {
    const float* x1 = (const float*)d_in[0];
    const float* x2 = (const float*)d_in[1];
    const float* gw = (const float*)d_in[2];
    const float* cw = (const float*)d_in[3];
    float* out = (float*)d_out;

    // workspace: x1t, x2t (fp16 [B][HW][C]) + x1f, x2f (bf16 [B][C][HW]) = 16 MB
    char* ws = (char*)d_ws;
    size_t elems = (size_t)BATCH * CCH * HWSZ;  // 2M
    _Float16* x1t = (_Float16*)ws;
    _Float16* x2t = (_Float16*)(ws + elems * 2);
    unsigned short* x1f = (unsigned short*)(ws + elems * 4);
    unsigned short* x2f = (unsigned short*)(ws + elems * 6);

    prep_kernel<<<4096, 256, 0, stream>>>(x1, x2, x1t, x2t, x1f, x2f);
    // out2 over m: softmax over n (columns), PV with x1f, elementwise x2
    fused_pass<0><<<256, 512, 0, stream>>>(x1t, x2t, x1f, x2, gw, cw, out);
    // out1 over n: softmax over m (rows), PV with x2f, elementwise x1
    fused_pass<1><<<256, 512, 0, stream>>>(x2t, x1t, x2f, x1, gw, cw, out);
}